// Round 7
// baseline (360.877 us; speedup 1.0000x reference)
//
#include <hip/hip_runtime.h>
#include <hip/hip_fp16.h>
#include <cstdint>
#include <cstddef>

#define B_ 4
#define S_ 4096
#define D_ 1024
#define E_ 1536
#define M_ (B_*S_)       // 16384
#define BE_ (B_*E_)      // 6144
#define C_ 32            // scan chunks
#define L_ (S_/C_)       // 128

typedef short bf16x8 __attribute__((ext_vector_type(8)));
typedef float f32x4 __attribute__((ext_vector_type(4)));

__device__ __forceinline__ unsigned short f2b(float f) {
  union { float f; unsigned int i; } x; x.f = f;
  unsigned int r = x.i + 0x7FFFu + ((x.i >> 16) & 1u);   // RNE
  return (unsigned short)(r >> 16);
}
__device__ __forceinline__ float h2f(unsigned short u) { return __half2float(__ushort_as_half(u)); }
__device__ __forceinline__ unsigned int packcv(float c, float v) {
  return (unsigned int)__half_as_ushort(__float2half_rn(c)) |
         ((unsigned int)__half_as_ushort(__float2half_rn(v)) << 16);
}
__device__ __forceinline__ void async16(const unsigned short* g, unsigned short* l) {
  __builtin_amdgcn_global_load_lds((const __attribute__((address_space(1))) unsigned int*)g,
                                   (__attribute__((address_space(3))) unsigned int*)l, 16, 0, 0);
}

// ---------- fp32 -> bf16 conversion, generic (1024 elems / block) ----------
__global__ __launch_bounds__(256) void cvt_bf16(const float* __restrict__ src,
                                                unsigned short* __restrict__ dst) {
  const int i = blockIdx.x * 256 + threadIdx.x;
  float4 f = ((const float4*)src)[i];
  ushort4 u; u.x = f2b(f.x); u.y = f2b(f.y); u.z = f2b(f.z); u.w = f2b(f.w);
  ((ushort4*)dst)[i] = u;
}

// ---------- fused conversion: x + W_hg (W_out must wait until CV is dead) ----------
#define NB_X   (M_*D_/1024)        // 16384 blocks
#define NB_WHG (2*E_*D_/1024)      // 3072
__global__ __launch_bounds__(256) void cvt_xw(const float* __restrict__ x, unsigned short* __restrict__ xb,
                                              const float* __restrict__ whg, unsigned short* __restrict__ wb) {
  int blk = blockIdx.x;
  const float* src; unsigned short* dst;
  if (blk < NB_X) { src = x; dst = xb; }
  else            { blk -= NB_X; src = whg; dst = wb; }
  const int i = blk * 256 + threadIdx.x;
  float4 f = ((const float4*)src)[i];
  ushort4 u; u.x = f2b(f.x); u.y = f2b(f.y); u.z = f2b(f.z); u.w = f2b(f.w);
  ((ushort4*)dst)[i] = u;
}

// ---------- GEMM1: 256m x 256n(=128h+128g) x BK=64, 8 waves, m201-style 8-phase schedule ----
// LDS = 8 half-tile slots x 16KB (128KB ring). Half stream per tile t: A0,A1,B0,B1 =
// H(4t..4t+3), slot = idx%8. One half staged per phase (2 gloads/thread: rows j*64+wv*8+
// (lane>>3), source col pre-swizzled scs=(lane&7)^(lane>>3) -> proven T2 pair with ds_read
// XOR (lm&7)). Per phase: {ds_read subtile; stage; s_barrier; [MFMA quadrant x16 under
// setprio]; s_barrier} with raw barriers (NO vmcnt drain). vmcnt(6)=3 halves in flight only
// at tile boundaries (P4): at tile tt, issued=8tt+22 loads, vmcnt(6) -> landed>=8tt+16 =
// tiles 0..tt+1 complete. Prologue: H0-3, vmcnt(4), H4-6, vmcnt(6), barrier.
// Quadrants: P1 afA(mf0-3)+bnA(B0,h) -> acc[mf][0-1]; P2 afB(mf4-7) -> acc[4+mf][0-1];
// P3 bnB(B1,g) -> acc[mf][2-3]; P4 -> acc[4+mf][2-3]. Wave owns h AND g of its e-cols
// (e = n0 + wn*32 + nf*16 + lm) -> round-4's VALIDATED epilogue (gate+pack+fused scan_p1)
// is reused verbatim.
__global__ __launch_bounds__(512) void gemm1_mfma(const unsigned short* __restrict__ Xb,
                                                  const unsigned short* __restrict__ Wb,
                                                  unsigned int* __restrict__ CV,
                                                  float* __restrict__ Pd,
                                                  float* __restrict__ Qfd,
                                                  float* __restrict__ Qrd) {
  __shared__ unsigned short sm[65536];   // 128 KB: slot s at s*8192 ushorts
  const int t = threadIdx.x;
  const int m0 = blockIdx.x * 256;
  const int n0 = blockIdx.y * 128;
  const int wv = t >> 6, lane = t & 63;
  const int wm = wv >> 2, wn = wv & 3;       // wm: 128-m half; wn: 32-e column group
  const int lm = lane & 15, kg = lane >> 4;
  const int l7 = lm & 7;
  const int r0 = wv * 8 + (lane >> 3);       // staging row within a 64-row issue
  const int scs = (lane & 7) ^ (lane >> 3);  // pre-swizzled source 16B col (row&7 == lane>>3)

  // staging source bases per half-kind (ushort units)
  const unsigned short* hk0 = Xb + (size_t)(m0 + r0) * D_ + scs * 8;          // A0: m 0-127
  const unsigned short* hk1 = Xb + (size_t)(m0 + 128 + r0) * D_ + scs * 8;    // A1: m 128-255
  const unsigned short* hk2 = Wb + (size_t)(n0 + r0) * D_ + scs * 8;          // B0: h rows
  const unsigned short* hk3 = Wb + (size_t)(E_ + n0 + r0) * D_ + scs * 8;     // B1: g rows

#define STAGE(s) do { \
    if ((s) < 64) { \
      const int kd_ = (s) & 3; const int ko_ = ((s) >> 2) * 64; \
      const unsigned short* sp_ = (kd_ == 0 ? hk0 : kd_ == 1 ? hk1 : kd_ == 2 ? hk2 : hk3) + ko_; \
      unsigned short* dp_ = sm + ((s) & 7) * 8192 + wv * 512; \
      async16(sp_, dp_); \
      async16(sp_ + (size_t)64 * D_, dp_ + 4096); \
    } \
  } while (0)

  const f32x4 z4 = {0.f, 0.f, 0.f, 0.f};
  f32x4 acc[8][4];
#pragma unroll
  for (int i = 0; i < 8; ++i)
#pragma unroll
    for (int j = 0; j < 4; ++j) acc[i][j] = z4;

  // prologue: tile0 (H0-3), vmcnt(4); tile1 A0,A1,B0 (H4-6), vmcnt(6); barrier
  STAGE(0); STAGE(1); STAGE(2); STAGE(3);
  asm volatile("s_waitcnt vmcnt(4)" ::: "memory");
  STAGE(4); STAGE(5); STAGE(6);
  asm volatile("s_waitcnt vmcnt(6)" ::: "memory");
  __builtin_amdgcn_s_barrier();
  __builtin_amdgcn_sched_barrier(0);

  bf16x8 afA[4][2], afB[4][2], bnA[2][2], bnB[2][2];
  const int cb0 = ((kg ^ l7) << 3);          // kh=0 swizzled col (ushort units)
  const int cb1 = (((4 | kg) ^ l7) << 3);    // kh=1

#pragma unroll 2
  for (int tt = 0; tt < 16; ++tt) {
    const int sb = (tt & 1) * 4;
    const unsigned short* sA  = sm + (sb + wm) * 8192;
    const unsigned short* sB0 = sm + (sb + 2) * 8192;
    const unsigned short* sB1 = sm + (sb + 3) * 8192;
    // ---------------- P1: afA + bnA, stage B1(t+1), MFMA q(0,0) ----------------
#pragma unroll
    for (int mf = 0; mf < 4; ++mf) {
      afA[mf][0] = *(const bf16x8*)(sA + (size_t)(mf * 16 + lm) * 64 + cb0);
      afA[mf][1] = *(const bf16x8*)(sA + (size_t)(mf * 16 + lm) * 64 + cb1);
    }
#pragma unroll
    for (int nf = 0; nf < 2; ++nf) {
      bnA[nf][0] = *(const bf16x8*)(sB0 + (size_t)(wn * 32 + nf * 16 + lm) * 64 + cb0);
      bnA[nf][1] = *(const bf16x8*)(sB0 + (size_t)(wn * 32 + nf * 16 + lm) * 64 + cb1);
    }
    STAGE(4 * tt + 7);
    __builtin_amdgcn_s_barrier();
    __builtin_amdgcn_sched_barrier(0);
    __builtin_amdgcn_s_setprio(1);
#pragma unroll
    for (int mf = 0; mf < 4; ++mf)
#pragma unroll
      for (int nf = 0; nf < 2; ++nf)
#pragma unroll
        for (int kh = 0; kh < 2; ++kh)
          acc[mf][nf] = __builtin_amdgcn_mfma_f32_16x16x32_bf16(afA[mf][kh], bnA[nf][kh], acc[mf][nf], 0, 0, 0);
    __builtin_amdgcn_s_setprio(0);
    __builtin_amdgcn_s_barrier();
    __builtin_amdgcn_sched_barrier(0);
    // ---------------- P2: afB, stage A0(t+2), MFMA q(1,0) ----------------
#pragma unroll
    for (int mf = 0; mf < 4; ++mf) {
      afB[mf][0] = *(const bf16x8*)(sA + (size_t)((mf + 4) * 16 + lm) * 64 + cb0);
      afB[mf][1] = *(const bf16x8*)(sA + (size_t)((mf + 4) * 16 + lm) * 64 + cb1);
    }
    STAGE(4 * tt + 8);
    __builtin_amdgcn_s_barrier();
    __builtin_amdgcn_sched_barrier(0);
    __builtin_amdgcn_s_setprio(1);
#pragma unroll
    for (int mf = 0; mf < 4; ++mf)
#pragma unroll
      for (int nf = 0; nf < 2; ++nf)
#pragma unroll
        for (int kh = 0; kh < 2; ++kh)
          acc[4 + mf][nf] = __builtin_amdgcn_mfma_f32_16x16x32_bf16(afB[mf][kh], bnA[nf][kh], acc[4 + mf][nf], 0, 0, 0);
    __builtin_amdgcn_s_setprio(0);
    __builtin_amdgcn_s_barrier();
    __builtin_amdgcn_sched_barrier(0);
    // ---------------- P3: bnB, stage A1(t+2), MFMA q(0,1) ----------------
#pragma unroll
    for (int nf = 0; nf < 2; ++nf) {
      bnB[nf][0] = *(const bf16x8*)(sB1 + (size_t)(wn * 32 + nf * 16 + lm) * 64 + cb0);
      bnB[nf][1] = *(const bf16x8*)(sB1 + (size_t)(wn * 32 + nf * 16 + lm) * 64 + cb1);
    }
    STAGE(4 * tt + 9);
    __builtin_amdgcn_s_barrier();
    __builtin_amdgcn_sched_barrier(0);
    __builtin_amdgcn_s_setprio(1);
#pragma unroll
    for (int mf = 0; mf < 4; ++mf)
#pragma unroll
      for (int nf = 0; nf < 2; ++nf)
#pragma unroll
        for (int kh = 0; kh < 2; ++kh)
          acc[mf][2 + nf] = __builtin_amdgcn_mfma_f32_16x16x32_bf16(afA[mf][kh], bnB[nf][kh], acc[mf][2 + nf], 0, 0, 0);
    __builtin_amdgcn_s_setprio(0);
    __builtin_amdgcn_s_barrier();
    __builtin_amdgcn_sched_barrier(0);
    // ---------------- P4: stage B0(t+2), vmcnt boundary, MFMA q(1,1) ----------------
    STAGE(4 * tt + 10);
    if (tt >= 14) asm volatile("s_waitcnt vmcnt(0)" ::: "memory");
    else          asm volatile("s_waitcnt vmcnt(6)" ::: "memory");
    __builtin_amdgcn_s_barrier();
    __builtin_amdgcn_sched_barrier(0);
    __builtin_amdgcn_s_setprio(1);
#pragma unroll
    for (int mf = 0; mf < 4; ++mf)
#pragma unroll
      for (int nf = 0; nf < 2; ++nf)
#pragma unroll
        for (int kh = 0; kh < 2; ++kh)
          acc[4 + mf][2 + nf] = __builtin_amdgcn_mfma_f32_16x16x32_bf16(afB[mf][kh], bnB[nf][kh], acc[4 + mf][2 + nf], 0, 0, 0);
    __builtin_amdgcn_s_setprio(0);
    __builtin_amdgcn_s_barrier();
    __builtin_amdgcn_sched_barrier(0);
  }
#undef STAGE

  __syncthreads();                            // loop fully drained (vmcnt(0) at tt=15); LDS free
  // epilogue (VALIDATED in round 4): gate+pack -> CV global + LDS sc[256m][128e]
  unsigned int* sc = (unsigned int*)sm;       // 128 KB
#pragma unroll
  for (int mf = 0; mf < 8; ++mf)
#pragma unroll
    for (int p = 0; p < 2; ++p) {
      const int eloc = wn * 32 + p * 16 + lm;
      const int e = n0 + eloc;
#pragma unroll
      for (int r = 0; r < 4; ++r) {
        const int mloc = wm * 128 + mf * 16 + kg * 4 + r;
        const float hid = acc[mf][p][r];
        const float gat = acc[mf][p + 2][r];
        const float z = 1.f / (1.f + __expf(-gat));
        const float cc = 1.f - z;
        const float gv = (hid >= 0.f) ? (hid + 0.5f) : (1.f / (1.f + __expf(-hid)));
        const unsigned int pk = packcv(cc, z * gv);
        CV[(size_t)(m0 + mloc) * E_ + e] = pk;
        sc[mloc * 128 + eloc] = pk;
      }
    }
  __syncthreads();
  // fused scan_p1: 2 chunks of 128 m; 4 segments of 32 m each; thread -> e = t&127, seg = t>>7
  const int er = t & 127, seg = t >> 7;
  float rp[2][3];
#pragma unroll
  for (int c = 0; c < 2; ++c) {
    float pp = 1.f, qf = 0.f, qr = 0.f;
#pragma unroll 8
    for (int l = 0; l < 32; ++l) {
      const unsigned int p = sc[(c * 128 + seg * 32 + l) * 128 + er];
      const float cv = h2f((unsigned short)p), vv = h2f((unsigned short)(p >> 16));
      qf = fmaf(cv, qf, vv);
      qr = fmaf(pp, vv, qr);
      pp *= cv;
    }
    rp[c][0] = pp; rp[c][1] = qf; rp[c][2] = qr;
  }
  __syncthreads();                            // all sc reads done before overwrite
  float* red = (float*)sm;                    // 2 chunks x 4 segs x 128 e x 3 = 12 KB
#pragma unroll
  for (int c = 0; c < 2; ++c) {
    red[c * 1536 + (seg * 128 + er) * 3 + 0] = rp[c][0];
    red[c * 1536 + (seg * 128 + er) * 3 + 1] = rp[c][1];
    red[c * 1536 + (seg * 128 + er) * 3 + 2] = rp[c][2];
  }
  __syncthreads();
  if (t < 256) {                              // chunk c = t>>7, e = t&127
    const int c = t >> 7, e = t & 127;
    float Pv = 1.f, Qfv = 0.f, Qrv = 0.f;
#pragma unroll
    for (int s = 0; s < 4; ++s) {
      const float ps  = red[c * 1536 + (s * 128 + e) * 3 + 0];
      const float qfs = red[c * 1536 + (s * 128 + e) * 3 + 1];
      const float qrs = red[c * 1536 + (s * 128 + e) * 3 + 2];
      Qfv = fmaf(ps, Qfv, qfs);
      Qrv = fmaf(Pv, qrs, Qrv);
      Pv *= ps;
    }
    const int kk = ((m0 & (S_ - 1)) >> 7) + c;
    const int be = (m0 >> 12) * E_ + n0 + e;
    Pd [(size_t)kk * BE_ + be] = Pv;
    Qfd[(size_t)kk * BE_ + be] = Qfv;
    Qrd[(size_t)kk * BE_ + be] = Qrv;
  }
}

// ---------- scan pass 2: chunk-level prefix (preloaded, fully unrolled) ----------
__global__ __launch_bounds__(256) void scan_p2(const float* __restrict__ P, const float* __restrict__ Qf,
                                               const float* __restrict__ Qr, float* __restrict__ HfIn,
                                               float* __restrict__ HbIn) {
  const int be = blockIdx.x * 256 + threadIdx.x;
  float Pk[C_], Qk[C_];
#pragma unroll
  for (int k = 0; k < C_; ++k) { Pk[k] = P[(size_t)k * BE_ + be]; Qk[k] = Qf[(size_t)k * BE_ + be]; }
  float hf = 0.f;
#pragma unroll
  for (int k = 0; k < C_; ++k) {
    HfIn[(size_t)k * BE_ + be] = hf;
    hf = fmaf(Pk[k], hf, Qk[k]);
  }
#pragma unroll
  for (int k = 0; k < C_; ++k) Qk[k] = Qr[(size_t)k * BE_ + be];
  float hb = 0.f;
#pragma unroll
  for (int k = C_ - 1; k >= 0; --k) {
    HbIn[(size_t)k * BE_ + be] = hb;   // state after consuming original chunks > k
    hb = fmaf(Pk[k], hb, Qk[k]);
  }
}

// ---------- scan pass 3 v2 (validated round 6): paired chunks, CV read ONCE, LDS-staged ----
__global__ __launch_bounds__(128) void scan_p3(const unsigned int* __restrict__ CV,
                                               const float* __restrict__ HfIn,
                                               const float* __restrict__ HbIn,
                                               unsigned short* __restrict__ Hb) {
  __shared__ unsigned int smU[2 * 128 * 64];   // 64KB: wave0's chunk at 0, wave1's at +8192
  const int t = threadIdx.x;
  const int wv = t >> 6, lane = t & 63;
  const int k = blockIdx.y, k2 = C_ - 1 - k;
  const int be0 = blockIdx.x * 64;
  const int b = be0 / E_, e0 = be0 - b * E_;   // slices never straddle b (E_ % 64 == 0)
  const int ck = wv ? k2 : k;                  // chunk this wave stages AND emits
  {
    const unsigned short* g = (const unsigned short*)
        (CV + ((size_t)b * S_ + (size_t)ck * L_ + (lane >> 4)) * E_ + e0 + (lane & 15) * 4);
    unsigned short* lb = (unsigned short*)smU + wv * 16384;
#pragma unroll
    for (int j = 0; j < 32; ++j)
      async16(g + (size_t)j * 4 * E_ * 2, lb + j * 512);
  }
  asm volatile("s_waitcnt vmcnt(0)" ::: "memory");
  __syncthreads();
  const unsigned int* Da = smU + (size_t)wv * 8192;        // own chunk, ascending
  const unsigned int* Db = smU + (size_t)(1 - wv) * 8192;  // partner chunk, descending
  const int be = b * E_ + e0 + lane;
  float hf = HfIn[(size_t)ck * BE_ + be];
  float hb = HbIn[(size_t)(C_ - 1 - ck) * BE_ + be];
  unsigned short* hp = Hb + ((size_t)b * S_ + (size_t)ck * L_) * E_ + e0 + lane;
#pragma unroll 8
  for (int l = 0; l < L_; ++l) {
    const unsigned int pf = Da[l * 64 + lane];
    const unsigned int pb = Db[(L_ - 1 - l) * 64 + lane];
    hf = fmaf(h2f((unsigned short)pf), hf, h2f((unsigned short)(pf >> 16)));
    hb = fmaf(h2f((unsigned short)pb), hb, h2f((unsigned short)(pb >> 16)));
    hp[(size_t)l * E_] = f2b(hf + hb);
  }
}

// ---------- GEMM2 (proven structure: 256 thr, BK=64, async staging, T2 swizzle) ----------
__global__ __launch_bounds__(256) void gemm2_mfma(const unsigned short* __restrict__ Hb,
                                                  const unsigned short* __restrict__ Wob,
                                                  float* __restrict__ Out) {
  __shared__ unsigned short lA[128 * 64];   // 16KB
  __shared__ unsigned short lB[128 * 64];   // 16KB
  const int t = threadIdx.x;
  const int m0 = blockIdx.x * 128;
  const int n0 = blockIdx.y * 128;
  const int wv = t >> 6, lane = t & 63;
  const int wm = wv >> 1, wn = wv & 1;
  const int lm = lane & 15, kg = lane >> 4;
  const int srow = lane >> 3;
  const int scs = (lane & 7) ^ srow;        // swizzled source 16B-column
  const bool stageA = (wv < 2);
  const unsigned short* gbase;
  if (stageA) gbase = Hb  + (size_t)(m0 + wv * 64 + srow) * E_ + scs * 8;
  else        gbase = Wob + (size_t)(n0 + (wv - 2) * 64 + srow) * E_ + scs * 8;
  unsigned short* lbase = (stageA ? lA : lB) + (size_t)(wv & 1) * 4096;

  const f32x4 z4 = {0.f, 0.f, 0.f, 0.f};
  f32x4 acc[4][4];
#pragma unroll
  for (int i = 0; i < 4; ++i)
#pragma unroll
    for (int j = 0; j < 4; ++j) acc[i][j] = z4;

  for (int k0 = 0; k0 < E_; k0 += 64) {
#pragma unroll
    for (int j = 0; j < 8; ++j)
      async16(gbase + k0 + (size_t)(j * 8) * E_, lbase + (size_t)j * 512);
    __syncthreads();
#pragma unroll
    for (int kh = 0; kh < 2; ++kh) {
      const int cb = ((((kh << 2) | kg) ^ (lm & 7)) << 3);   // swizzled col (ushort units)
      bf16x8 af[4], bfr[4];
#pragma unroll
      for (int mt = 0; mt < 4; ++mt)
        af[mt] = *(const bf16x8*)(lA + (size_t)(wm * 64 + mt * 16 + lm) * 64 + cb);
#pragma unroll
      for (int nt = 0; nt < 4; ++nt)
        bfr[nt] = *(const bf16x8*)(lB + (size_t)(wn * 64 + nt * 16 + lm) * 64 + cb);
#pragma unroll
      for (int mt = 0; mt < 4; ++mt)
#pragma unroll
        for (int nt = 0; nt < 4; ++nt)
          acc[mt][nt] = __builtin_amdgcn_mfma_f32_16x16x32_bf16(af[mt], bfr[nt], acc[mt][nt], 0, 0, 0);
    }
    __syncthreads();
  }
#pragma unroll
  for (int mt = 0; mt < 4; ++mt)
#pragma unroll
    for (int nt = 0; nt < 4; ++nt) {
      const int d = n0 + wn * 64 + nt * 16 + lm;
#pragma unroll
      for (int r = 0; r < 4; ++r) {
        const int m = m0 + wm * 64 + mt * 16 + kg * 4 + r;
        Out[(size_t)m * D_ + d] = acc[mt][nt][r];
      }
    }
}

extern "C" void kernel_launch(void* const* d_in, const int* in_sizes, int n_in,
                              void* d_out, int out_size, void* d_ws, size_t ws_size,
                              hipStream_t stream) {
  const float* x    = (const float*)d_in[0];
  const float* whg  = (const float*)d_in[1];
  const float* wout = (const float*)d_in[2];
  float* out = (float*)d_out;

  // ws (151 MB, proven-safe): [CV: M*E*4][H: M*E*2]
  unsigned int*  CV = (unsigned int*)d_ws;
  unsigned short* Hb = (unsigned short*)((char*)d_ws + (size_t)M_ * E_ * 4);
  unsigned short* Xb  = Hb;                     // bf16 X in H region until scan writes H
  unsigned short* Wb  = Xb + (size_t)M_ * D_;
  unsigned short* Wob = (unsigned short*)d_ws;  // bf16 W_out in CV region — ONLY after scans done
  // scan chunk scratch in d_out (gemm2 fully overwrites)
  float* P    = out;
  float* Qf   = out + (size_t)C_ * BE_;
  float* Qr   = out + 2 * (size_t)C_ * BE_;
  float* HfIn = out + 3 * (size_t)C_ * BE_;
  float* HbIn = out + 4 * (size_t)C_ * BE_;

  cvt_xw<<<NB_X + NB_WHG, 256, 0, stream>>>(x, Xb, whg, Wb);
  gemm1_mfma<<<dim3(M_ / 256, E_ / 128), 512, 0, stream>>>(Xb, Wb, CV, P, Qf, Qr);
  scan_p2<<<BE_ / 256, 256, 0, stream>>>(P, Qf, Qr, HfIn, HbIn);
  scan_p3<<<dim3(BE_ / 64, C_ / 2), 128, 0, stream>>>(CV, HfIn, HbIn, Hb);
  cvt_bf16<<<D_ * E_ / 1024, 256, 0, stream>>>(wout, Wob);   // CV dead now
  gemm2_mfma<<<dim3(M_ / 128, D_ / 128), 256, 0, stream>>>(Hb, Wob, out);
}